// Round 6
// baseline (349.628 us; speedup 1.0000x reference)
//
#include <hip/hip_runtime.h>

#define BB 8
#define SS 4096
#define HIDD 1024
#define HH 16
#define DHH 64

typedef __attribute__((ext_vector_type(8))) short bf16x8;
typedef __attribute__((ext_vector_type(4))) float f32x4;

static __device__ __forceinline__ unsigned short f2bf(float x) {
    union { float f; unsigned int u; } a; a.f = x;
    unsigned int r = a.u + 0x7FFFu + ((a.u >> 16) & 1u);   // RTN-even
    return (unsigned short)(r >> 16);
}
static __device__ __forceinline__ float bf2f(unsigned short b) {
    union { unsigned int u; float f; } a; a.u = ((unsigned int)b) << 16;
    return a.f;
}

// K1 v2: weff[o][k] = sum_d aw[o&15,d]*W[(o&15)*64+d, k] (W = Wq for o<16, Wk else),
// written DIRECTLY in MFMA B-fragment order, split bf16 hi/lo:
// bpack frag index (kk*4 + p*2 + nt), kk=K-step(32-wide), p=hi/lo, nt=out-tile;
// within frag: lane = ((k>>3)&3)*16 + (o&15), ushort j = k&7.
// grid (4,16,2), block 256.
__global__ __launch_bounds__(256) void k_prep(const float* __restrict__ Wq,
                                              const float* __restrict__ Wk,
                                              const float* __restrict__ aw,
                                              unsigned short* __restrict__ bpack) {
    int k = blockIdx.x * 256 + threadIdx.x;    // 0..1023
    int h = blockIdx.y;                        // 0..15
    const float* W = blockIdx.z ? Wk : Wq;
    int nt = blockIdx.z;                       // 0 = q heads, 1 = k heads
    float acc = 0.f;
#pragma unroll
    for (int d = 0; d < DHH; ++d) {
        acc += aw[h * DHH + d] * W[(size_t)(h * DHH + d) * HIDD + k];
    }
    unsigned short hi = f2bf(acc);
    unsigned short lo = f2bf(acc - bf2f(hi));
    int kk   = k >> 5;
    int r5   = (k >> 3) & 3;
    int j    = k & 7;
    int lane = r5 * 16 + h;
    size_t baseh = ((size_t)(kk * 4 + 0 + nt) * 256 + lane * 4) * 2 + j;
    size_t basel = ((size_t)(kk * 4 + 2 + nt) * 256 + lane * 4) * 2 + j;
    bpack[baseh] = hi;
    bpack[basel] = lo;
}

// K2 v9: scores[32768][32] = hid x weff^T via MFMA 16x16x32 bf16, split-precision
// (hihi + lohi + hilo; lo*lo dropped, err ~3e-6 << 1e-3 budget).
// Rounds 3-5 lesson: VALU-FMA needs ~3.1M DS wave-instrs (2.1M broadcast weight
// reads) = ~60us DS-pipe floor. MFMA + B-frags from GLOBAL (coalesced 16B/lane,
// 128KB L2-resident) eliminates broadcasts entirely.
// Block 256 = 4 waves; wave = 16 rows x 32 outs; block = 64 rows; grid 512
// (2 blocks/CU, LDS 34KB). hid staged fp32 in LDS stride-17-f4 rows (<=2-way
// banks), each element ds_read + hi/lo-converted exactly once.
// A-frag: lane holds hid[wave*16 + (lane&15)][k0 + 8*(lane>>4) + 0..7].
// C layout (m89-verified): col = lane&15 (out), row = (lane>>4)*4 + reg.
#define KC 64
__global__ __launch_bounds__(256) void k_scores(const float* __restrict__ hid,
                                                const float* __restrict__ mask,
                                                const unsigned short* __restrict__ bpack,
                                                float* __restrict__ qsb,
                                                float* __restrict__ ksb) {
    __shared__ float shh[2][64 * 68];     // 2 x 17408 floats, row stride 17 f4

    const int t    = threadIdx.x;         // 0..255
    const int lane = t & 63;
    const int wave = t >> 6;              // 0..3
    const int rbase = blockIdx.x * 64;
    const size_t gbase = (size_t)rbase * HIDD;

    // staging: 64 rows x 17 f4-slots = 1088 slots; 4/thread + 1 extra for t<64.
    int srow[5], scol[5];
#pragma unroll
    for (int j = 0; j < 5; ++j) {
        int f = (j < 4) ? (j * 256 + t) : (1024 + t);
        int r = f / 17;
        int c = f - r * 17;
        srow[j] = r;
        scol[j] = (c == 16) ? 0 : c;
    }
    const bool extra = (t < 64);

    auto stage = [&](int chunk, int buf) {
#pragma unroll
        for (int j = 0; j < 4; ++j) {
            const float* gp = hid + gbase + (size_t)srow[j] * HIDD
                              + chunk * KC + scol[j] * 4;
            float* lp = &shh[buf][(j * 256 + t) * 4];
            __builtin_amdgcn_global_load_lds(
                (const __attribute__((address_space(1))) void*)gp,
                (__attribute__((address_space(3))) void*)lp, 16, 0, 0);
        }
        if (extra) {
            const float* gp = hid + gbase + (size_t)srow[4] * HIDD
                              + chunk * KC + scol[4] * 4;
            float* lp = &shh[buf][(1024 + t) * 4];
            __builtin_amdgcn_global_load_lds(
                (const __attribute__((address_space(1))) void*)gp,
                (__attribute__((address_space(3))) void*)lp, 16, 0, 0);
        }
    };

    const bf16x8* bview = reinterpret_cast<const bf16x8*>(bpack);
    const int mrow = wave * 16 + (lane & 15);   // block-local A row
    const int koff = (lane >> 4) * 8;           // k sub-offset within 32

    f32x4 accq = {0.f, 0.f, 0.f, 0.f};
    f32x4 acck = {0.f, 0.f, 0.f, 0.f};

    stage(0, 0);

    for (int chunk = 0; chunk < HIDD / KC; ++chunk) {
        const int buf = chunk & 1;
        asm volatile("s_waitcnt vmcnt(0)" ::: "memory");  // own stage done
        __syncthreads();                                  // all stages done
        if (chunk + 1 < HIDD / KC) stage(chunk + 1, buf ^ 1);

#pragma unroll
        for (int kl = 0; kl < 2; ++kl) {
            const int kk = chunk * 2 + kl;
            // B fragments: coalesced 16B/lane from L2-resident bpack
            bf16x8 bh0 = bview[(kk * 4 + 0) * 64 + lane];
            bf16x8 bh1 = bview[(kk * 4 + 1) * 64 + lane];
            bf16x8 bl0 = bview[(kk * 4 + 2) * 64 + lane];
            bf16x8 bl1 = bview[(kk * 4 + 3) * 64 + lane];

            // A: 8 consecutive fp32 from LDS (2x b128), convert hi/lo once
            const float* ap = &shh[buf][mrow * 68 + kl * 32 + koff];
            float4 av0 = *reinterpret_cast<const float4*>(ap);
            float4 av1 = *reinterpret_cast<const float4*>(ap + 4);
            float a[8] = {av0.x, av0.y, av0.z, av0.w, av1.x, av1.y, av1.z, av1.w};
            union { bf16x8 v; unsigned short u[8]; } Ahi, Alo;
#pragma unroll
            for (int j = 0; j < 8; ++j) {
                unsigned short hb = f2bf(a[j]);
                Ahi.u[j] = hb;
                Alo.u[j] = f2bf(a[j] - bf2f(hb));
            }

            accq = __builtin_amdgcn_mfma_f32_16x16x32_bf16(Ahi.v, bh0, accq, 0, 0, 0);
            accq = __builtin_amdgcn_mfma_f32_16x16x32_bf16(Alo.v, bh0, accq, 0, 0, 0);
            accq = __builtin_amdgcn_mfma_f32_16x16x32_bf16(Ahi.v, bl0, accq, 0, 0, 0);
            acck = __builtin_amdgcn_mfma_f32_16x16x32_bf16(Ahi.v, bh1, acck, 0, 0, 0);
            acck = __builtin_amdgcn_mfma_f32_16x16x32_bf16(Alo.v, bh1, acck, 0, 0, 0);
            acck = __builtin_amdgcn_mfma_f32_16x16x32_bf16(Ahi.v, bl1, acck, 0, 0, 0);
        }
    }

    // C layout: col = lane&15 (out within tile), row = (lane>>4)*4 + reg
#pragma unroll
    for (int reg = 0; reg < 4; ++reg) {
        int grow = rbase + wave * 16 + (lane >> 4) * 4 + reg;
        float m = mask[grow];
        qsb[(size_t)grow * 16 + (lane & 15)] = accq[reg] * m;
        ksb[(size_t)grow * 20 + (lane & 15)] = acck[reg] * m;
        if ((lane & 15) == 0) ksb[(size_t)grow * 20 + 16] = m;
    }
}

// K3 v3: NO atomics. Thread owns 4 cols (float4 loads, 68 accumulators),
// s-chunk 64 rows -> grid (64, 8) = 512 blocks = 2/CU.
// part[schunk][b][17][1024]: ksh partial (16 ch) + hsum partial (mask ch).
__global__ __launch_bounds__(256) void k_ksh(const float* __restrict__ hid,
                                             const float* __restrict__ ksb,
                                             float* __restrict__ part) {
    int b  = blockIdx.y;
    int i  = threadIdx.x * 4;
    int s0 = blockIdx.x * 64;

    float4 acc[17];
#pragma unroll
    for (int c = 0; c < 17; ++c) acc[c] = make_float4(0.f, 0.f, 0.f, 0.f);

    const float* hb = hid + (size_t)(b * SS + s0) * HIDD + i;
    const float* sb = ksb + (size_t)(b * SS + s0) * 20;

#pragma unroll 4
    for (int s = 0; s < 64; ++s) {
        float4 hv = *reinterpret_cast<const float4*>(hb + (size_t)s * HIDD);
        const float* sc = sb + s * 20;
#pragma unroll
        for (int c = 0; c < 17; ++c) {
            float scv = sc[c];
            acc[c].x += scv * hv.x;
            acc[c].y += scv * hv.y;
            acc[c].z += scv * hv.z;
            acc[c].w += scv * hv.w;
        }
    }

    float* pb = part + (((size_t)blockIdx.x * 8 + b) * 17) * 1024 + i;
#pragma unroll
    for (int c = 0; c < 17; ++c) {
        *reinterpret_cast<float4*>(pb + c * 1024) = acc[c];
    }
}

// K3b: reduce 64 schunk partials -> ksh[b][16][1024], hsum[b][1024].
// grid 544, block 256 (544*256 = 8*17*1024 outputs exactly)
__global__ __launch_bounds__(256) void k_red(const float* __restrict__ part,
                                             float* __restrict__ ksh,
                                             float* __restrict__ hsum) {
    int gid = blockIdx.x * 256 + threadIdx.x;
    int b = gid / 17408;               // 17*1024
    int r = gid - b * 17408;
    int c = r >> 10;
    int i = r & 1023;

    float s = 0.f;
#pragma unroll 8
    for (int k = 0; k < 64; ++k)
        s += part[(((size_t)k * 8 + b) * 17 + c) * 1024 + i];

    if (c < 16) ksh[((size_t)b * 16 + c) * 1024 + i] = s;
    else        hsum[b * 1024 + i] = s;
}

// K4 v2: mvn[b,j] = (Wv[j,:]·hsum[b,:])/len;  kvn[b,j] = (Wv[j,:]·ksh[b,j/64,:])/len
// grid (8, 32), block 256: 32 j per block, 8 lanes split each 1024-dot,
// __shfl_xor reduce over the 8-lane group.
__global__ __launch_bounds__(256) void k_fin(const float* __restrict__ Wv,
                                             const float* __restrict__ mask,
                                             const float* __restrict__ hsum,
                                             const float* __restrict__ ksh,
                                             float* __restrict__ mvn,
                                             float* __restrict__ kvn) {
    int b  = blockIdx.x;
    int j  = blockIdx.y * 32 + (threadIdx.x >> 3);
    int sl = threadIdx.x & 7;

    __shared__ float red[256];
    float lsum = 0.f;
    for (int s = threadIdx.x; s < SS; s += 256) lsum += mask[b * SS + s];
    red[threadIdx.x] = lsum;
    __syncthreads();
    for (int off = 128; off; off >>= 1) {
        if (threadIdx.x < off) red[threadIdx.x] += red[threadIdx.x + off];
        __syncthreads();
    }
    float invlen = 1.0f / red[0];

    int h = j >> 6;
    const float4* w4 = reinterpret_cast<const float4*>(Wv + (size_t)j * HIDD + sl * 128);
    const float4* hv = reinterpret_cast<const float4*>(hsum + b * HIDD + sl * 128);
    const float4* kv = reinterpret_cast<const float4*>(ksh + ((size_t)b * 16 + h) * HIDD + sl * 128);

    float mv = 0.f, kvv = 0.f;
#pragma unroll
    for (int c = 0; c < 32; ++c) {
        float4 w = w4[c], a = hv[c], k2 = kv[c];
        mv  += w.x * a.x  + w.y * a.y  + w.z * a.z  + w.w * a.w;
        kvv += w.x * k2.x + w.y * k2.y + w.z * k2.z + w.w * k2.w;
    }
#pragma unroll
    for (int off = 1; off < 8; off <<= 1) {
        mv  += __shfl_xor(mv, off);
        kvv += __shfl_xor(kvv, off);
    }
    if (sl == 0) {
        mvn[b * HIDD + j] = mv * invlen;
        kvn[b * HIDD + j] = kvv * invlen;
    }
}

// K5: out[b,s,j] = q_score[b,s,j/64]*mvn[b,j] + kvn[b,j], float4 stores.
// grid 16384, block 256, 8 elems/thread
__global__ __launch_bounds__(256) void k_out(const float* __restrict__ qsb,
                                             const float* __restrict__ mvn,
                                             const float* __restrict__ kvn,
                                             float* __restrict__ outp) {
    size_t e0 = ((size_t)blockIdx.x * 256 + threadIdx.x) * 8;
    int b   = (int)(e0 >> 22);                 // 4096*1024 = 2^22
    int rem = (int)(e0 & ((1u << 22) - 1));
    int s   = rem >> 10;
    int j   = rem & 1023;

    float q = qsb[(size_t)(b * SS + s) * 16 + (j >> 6)];
    const float4* mv4 = reinterpret_cast<const float4*>(mvn + b * HIDD + j);
    const float4* kv4 = reinterpret_cast<const float4*>(kvn + b * HIDD + j);
    float4 m0 = mv4[0], m1 = mv4[1];
    float4 k0 = kv4[0], k1 = kv4[1];

    float4 o0, o1;
    o0.x = q * m0.x + k0.x;  o0.y = q * m0.y + k0.y;
    o0.z = q * m0.z + k0.z;  o0.w = q * m0.w + k0.w;
    o1.x = q * m1.x + k1.x;  o1.y = q * m1.y + k1.y;
    o1.z = q * m1.z + k1.z;  o1.w = q * m1.w + k1.w;

    float4* op = reinterpret_cast<float4*>(outp + e0);
    op[0] = o0;
    op[1] = o1;
}

extern "C" void kernel_launch(void* const* d_in, const int* in_sizes, int n_in,
                              void* d_out, int out_size, void* d_ws, size_t ws_size,
                              hipStream_t stream) {
    const float* hid  = (const float*)d_in[0];   // (B,S,HID)
    const float* mask = (const float*)d_in[1];   // (B,1,1,S)
    const float* Wq   = (const float*)d_in[2];   // (HID,HID)
    const float* Wk   = (const float*)d_in[3];
    const float* Wv   = (const float*)d_in[4];
    const float* aw   = (const float*)d_in[5];   // (H,1,DH)
    float* outp = (float*)d_out;

    float* ws   = (float*)d_ws;
    unsigned short* bpack = (unsigned short*)ws; // 65536 ushort = 32768 floats
    float* qsb  = ws + 32768;               // 8*4096*16 = 524288
    float* ksb  = qsb + 524288;             // 8*4096*20 = 655360
    float* ksh  = ksb + 655360;             // 8*16*1024 = 131072
    float* hsum = ksh + 131072;             // 8*1024   = 8192
    float* mvn  = hsum + 8192;              // 8192
    float* kvn  = mvn + 8192;               // 8192
    float* part = kvn + 8192;               // 64*8*17*1024 = 8912896 (~35.7 MB)

    k_prep  <<<dim3(4, 16, 2), 256, 0, stream>>>(Wq, Wk, aw, bpack);
    k_scores<<<dim3(512),      256, 0, stream>>>(hid, mask, bpack, qsb, ksb);
    k_ksh   <<<dim3(64, 8),    256, 0, stream>>>(hid, ksb, part);
    k_red   <<<dim3(544),      256, 0, stream>>>(part, ksh, hsum);
    k_fin   <<<dim3(8, 32),    256, 0, stream>>>(Wv, mask, hsum, ksh, mvn, kvn);
    k_out   <<<dim3(16384),    256, 0, stream>>>(qsb, mvn, kvn, outp);
}

// Round 7
// 346.990 us; speedup vs baseline: 1.0076x; 1.0076x over previous
//
#include <hip/hip_runtime.h>

#define BB 8
#define SS 4096
#define HIDD 1024
#define HH 16
#define DHH 64

typedef __attribute__((ext_vector_type(8))) short bf16x8;
typedef __attribute__((ext_vector_type(4))) float f32x4;

static __device__ __forceinline__ unsigned short f2bf(float x) {
    union { float f; unsigned int u; } a; a.f = x;
    unsigned int r = a.u + 0x7FFFu + ((a.u >> 16) & 1u);   // RTN-even
    return (unsigned short)(r >> 16);
}
static __device__ __forceinline__ float bf2f(unsigned short b) {
    union { unsigned int u; float f; } a; a.u = ((unsigned int)b) << 16;
    return a.f;
}

// K1 v2: weff[o][k] = sum_d aw[o&15,d]*W[(o&15)*64+d, k] (W = Wq for o<16, Wk else),
// written DIRECTLY in MFMA B-fragment order, split bf16 hi/lo:
// bpack frag index (kk*4 + p*2 + nt), kk=K-step(32-wide), p=hi/lo, nt=out-tile;
// within frag: lane = ((k>>3)&3)*16 + (o&15), ushort j = k&7.
// grid (4,16,2), block 256.
__global__ __launch_bounds__(256) void k_prep(const float* __restrict__ Wq,
                                              const float* __restrict__ Wk,
                                              const float* __restrict__ aw,
                                              unsigned short* __restrict__ bpack) {
    int k = blockIdx.x * 256 + threadIdx.x;    // 0..1023
    int h = blockIdx.y;                        // 0..15
    const float* W = blockIdx.z ? Wk : Wq;
    int nt = blockIdx.z;                       // 0 = q heads, 1 = k heads
    float acc = 0.f;
#pragma unroll
    for (int d = 0; d < DHH; ++d) {
        acc += aw[h * DHH + d] * W[(size_t)(h * DHH + d) * HIDD + k];
    }
    unsigned short hi = f2bf(acc);
    unsigned short lo = f2bf(acc - bf2f(hi));
    int kk   = k >> 5;
    int r5   = (k >> 3) & 3;
    int j    = k & 7;
    int lane = r5 * 16 + h;
    size_t baseh = ((size_t)(kk * 4 + 0 + nt) * 256 + lane * 4) * 2 + j;
    size_t basel = ((size_t)(kk * 4 + 2 + nt) * 256 + lane * 4) * 2 + j;
    bpack[baseh] = hi;
    bpack[basel] = lo;
}

// K2 v10 = v9 (MFMA split-bf16) + T3/T4 pipeline.
// Round-6 discovery: __syncthreads() emits s_waitcnt vmcnt(0) before s_barrier
// -> every chunk fully drained the staging queue; all of rounds 1-6 were
// pinned at ~80us by this single drain regardless of inner-loop structure.
// Fix: RAW __builtin_amdgcn_s_barrier() + counted s_waitcnt vmcnt(5)
// (= one 5-instr stage still in flight; never 0 in the main loop) +
// sched_barrier(0) fences so hipcc can't hoist VMEM across the wait.
// Triple-buffer LDS (3 x 17KB): while computing chunk c, stages c+1 and c+2
// are in flight (2-deep, 68KB/CU in flight >> Little's-law 12KB).
// Staging is exactly 5 wave-uniform VMEM instrs/stage: 4 full + 1 with
// lane<16 exec-mask (exec!=0 -> still counts 1 in vmcnt for every wave).
// Safety: each wave waits OWN vmcnt -> its LDS writes done -> barrier ->
// whole chunk visible. ds_reads are consumed by conversions pre-barrier.
// Buffers: read c%3, in-flight (c+1)%3,(c+2)%3 - all distinct.
#define KC 64
#define NCH (HIDD / KC)
__global__ __launch_bounds__(256) void k_scores(const float* __restrict__ hid,
                                                const float* __restrict__ mask,
                                                const unsigned short* __restrict__ bpack,
                                                float* __restrict__ qsb,
                                                float* __restrict__ ksb) {
    __shared__ float shh[3][64 * 68];     // 3 x 17408 B, row stride 17 f4

    const int t    = threadIdx.x;         // 0..255
    const int lane = t & 63;
    const int wave = t >> 6;              // 0..3
    const int rbase = blockIdx.x * 64;
    const size_t gbase = (size_t)rbase * HIDD;

    // staging slots: 64 rows x 17 f4 = 1088. 4/thread (f = j*256+t) plus
    // slot 1024 + wave*16 + lane for lane<16 (per-wave 5th instr, exec-masked).
    int srow[5], scol[5], sslot[5];
#pragma unroll
    for (int j = 0; j < 5; ++j) {
        int f = (j < 4) ? (j * 256 + t) : (1024 + wave * 16 + (lane & 15));
        int r = f / 17;
        int c = f - r * 17;
        srow[j]  = r;
        scol[j]  = (c == 16) ? 0 : c;
        sslot[j] = f;
    }

    auto stage = [&](int chunk, int buf) {
#pragma unroll
        for (int j = 0; j < 4; ++j) {
            const float* gp = hid + gbase + (size_t)srow[j] * HIDD
                              + chunk * KC + scol[j] * 4;
            float* lp = &shh[buf][sslot[j] * 4];
            __builtin_amdgcn_global_load_lds(
                (const __attribute__((address_space(1))) void*)gp,
                (__attribute__((address_space(3))) void*)lp, 16, 0, 0);
        }
        if (lane < 16) {
            const float* gp = hid + gbase + (size_t)srow[4] * HIDD
                              + chunk * KC + scol[4] * 4;
            float* lp = &shh[buf][sslot[4] * 4];
            __builtin_amdgcn_global_load_lds(
                (const __attribute__((address_space(1))) void*)gp,
                (__attribute__((address_space(3))) void*)lp, 16, 0, 0);
        }
    };

    const bf16x8* bview = reinterpret_cast<const bf16x8*>(bpack);
    const int mrow = wave * 16 + (lane & 15);   // block-local A row
    const int koff = (lane >> 4) * 8;           // k sub-offset within 32

    f32x4 accq = {0.f, 0.f, 0.f, 0.f};
    f32x4 acck = {0.f, 0.f, 0.f, 0.f};

    stage(0, 0);
    stage(1, 1);

    int cbuf = 0;
    for (int chunk = 0; chunk < NCH; ++chunk) {
        __builtin_amdgcn_sched_barrier(0);
        if (chunk < NCH - 1) {
            asm volatile("s_waitcnt vmcnt(5)" ::: "memory");   // stage(chunk) done
        } else {
            asm volatile("s_waitcnt vmcnt(0)" ::: "memory");   // final drain
        }
        __builtin_amdgcn_s_barrier();          // RAW barrier - no implicit drain
        __builtin_amdgcn_sched_barrier(0);
        if (chunk + 2 < NCH) {
            int sbuf = (cbuf == 0) ? 2 : cbuf - 1;   // (chunk+2)%3
            stage(chunk + 2, sbuf);
        }

#pragma unroll
        for (int kl = 0; kl < 2; ++kl) {
            const int kk = chunk * 2 + kl;
            // B fragments: coalesced 16B/lane from L2-resident bpack
            bf16x8 bh0 = bview[(kk * 4 + 0) * 64 + lane];
            bf16x8 bh1 = bview[(kk * 4 + 1) * 64 + lane];
            bf16x8 bl0 = bview[(kk * 4 + 2) * 64 + lane];
            bf16x8 bl1 = bview[(kk * 4 + 3) * 64 + lane];

            // A: 8 consecutive fp32 from LDS (2x b128), convert hi/lo once
            const float* ap = &shh[cbuf][mrow * 68 + kl * 32 + koff];
            float4 av0 = *reinterpret_cast<const float4*>(ap);
            float4 av1 = *reinterpret_cast<const float4*>(ap + 4);
            float a[8] = {av0.x, av0.y, av0.z, av0.w, av1.x, av1.y, av1.z, av1.w};
            union { bf16x8 v; unsigned short u[8]; } Ahi, Alo;
#pragma unroll
            for (int j = 0; j < 8; ++j) {
                unsigned short hb = f2bf(a[j]);
                Ahi.u[j] = hb;
                Alo.u[j] = f2bf(a[j] - bf2f(hb));
            }

            accq = __builtin_amdgcn_mfma_f32_16x16x32_bf16(Ahi.v, bh0, accq, 0, 0, 0);
            accq = __builtin_amdgcn_mfma_f32_16x16x32_bf16(Alo.v, bh0, accq, 0, 0, 0);
            accq = __builtin_amdgcn_mfma_f32_16x16x32_bf16(Ahi.v, bl0, accq, 0, 0, 0);
            acck = __builtin_amdgcn_mfma_f32_16x16x32_bf16(Ahi.v, bh1, acck, 0, 0, 0);
            acck = __builtin_amdgcn_mfma_f32_16x16x32_bf16(Alo.v, bh1, acck, 0, 0, 0);
            acck = __builtin_amdgcn_mfma_f32_16x16x32_bf16(Ahi.v, bl1, acck, 0, 0, 0);
        }
        cbuf = (cbuf == 2) ? 0 : cbuf + 1;
    }

    // C layout (m89-verified): col = lane&15 (out), row = (lane>>4)*4 + reg
#pragma unroll
    for (int reg = 0; reg < 4; ++reg) {
        int grow = rbase + wave * 16 + (lane >> 4) * 4 + reg;
        float m = mask[grow];
        qsb[(size_t)grow * 16 + (lane & 15)] = accq[reg] * m;
        ksb[(size_t)grow * 20 + (lane & 15)] = acck[reg] * m;
        if ((lane & 15) == 0) ksb[(size_t)grow * 20 + 16] = m;
    }
}

// K3 v3: NO atomics. Thread owns 4 cols (float4 loads, 68 accumulators),
// s-chunk 64 rows -> grid (64, 8) = 512 blocks = 2/CU.
// part[schunk][b][17][1024]: ksh partial (16 ch) + hsum partial (mask ch).
__global__ __launch_bounds__(256) void k_ksh(const float* __restrict__ hid,
                                             const float* __restrict__ ksb,
                                             float* __restrict__ part) {
    int b  = blockIdx.y;
    int i  = threadIdx.x * 4;
    int s0 = blockIdx.x * 64;

    float4 acc[17];
#pragma unroll
    for (int c = 0; c < 17; ++c) acc[c] = make_float4(0.f, 0.f, 0.f, 0.f);

    const float* hb = hid + (size_t)(b * SS + s0) * HIDD + i;
    const float* sb = ksb + (size_t)(b * SS + s0) * 20;

#pragma unroll 4
    for (int s = 0; s < 64; ++s) {
        float4 hv = *reinterpret_cast<const float4*>(hb + (size_t)s * HIDD);
        const float* sc = sb + s * 20;
#pragma unroll
        for (int c = 0; c < 17; ++c) {
            float scv = sc[c];
            acc[c].x += scv * hv.x;
            acc[c].y += scv * hv.y;
            acc[c].z += scv * hv.z;
            acc[c].w += scv * hv.w;
        }
    }

    float* pb = part + (((size_t)blockIdx.x * 8 + b) * 17) * 1024 + i;
#pragma unroll
    for (int c = 0; c < 17; ++c) {
        *reinterpret_cast<float4*>(pb + c * 1024) = acc[c];
    }
}

// K3b: reduce 64 schunk partials -> ksh[b][16][1024], hsum[b][1024].
// grid 544, block 256 (544*256 = 8*17*1024 outputs exactly)
__global__ __launch_bounds__(256) void k_red(const float* __restrict__ part,
                                             float* __restrict__ ksh,
                                             float* __restrict__ hsum) {
    int gid = blockIdx.x * 256 + threadIdx.x;
    int b = gid / 17408;               // 17*1024
    int r = gid - b * 17408;
    int c = r >> 10;
    int i = r & 1023;

    float s = 0.f;
#pragma unroll 8
    for (int k = 0; k < 64; ++k)
        s += part[(((size_t)k * 8 + b) * 17 + c) * 1024 + i];

    if (c < 16) ksh[((size_t)b * 16 + c) * 1024 + i] = s;
    else        hsum[b * 1024 + i] = s;
}

// K4 v2: mvn[b,j] = (Wv[j,:]·hsum[b,:])/len;  kvn[b,j] = (Wv[j,:]·ksh[b,j/64,:])/len
// grid (8, 32), block 256: 32 j per block, 8 lanes split each 1024-dot,
// __shfl_xor reduce over the 8-lane group.
__global__ __launch_bounds__(256) void k_fin(const float* __restrict__ Wv,
                                             const float* __restrict__ mask,
                                             const float* __restrict__ hsum,
                                             const float* __restrict__ ksh,
                                             float* __restrict__ mvn,
                                             float* __restrict__ kvn) {
    int b  = blockIdx.x;
    int j  = blockIdx.y * 32 + (threadIdx.x >> 3);
    int sl = threadIdx.x & 7;

    __shared__ float red[256];
    float lsum = 0.f;
    for (int s = threadIdx.x; s < SS; s += 256) lsum += mask[b * SS + s];
    red[threadIdx.x] = lsum;
    __syncthreads();
    for (int off = 128; off; off >>= 1) {
        if (threadIdx.x < off) red[threadIdx.x] += red[threadIdx.x + off];
        __syncthreads();
    }
    float invlen = 1.0f / red[0];

    int h = j >> 6;
    const float4* w4 = reinterpret_cast<const float4*>(Wv + (size_t)j * HIDD + sl * 128);
    const float4* hv = reinterpret_cast<const float4*>(hsum + b * HIDD + sl * 128);
    const float4* kv = reinterpret_cast<const float4*>(ksh + ((size_t)b * 16 + h) * HIDD + sl * 128);

    float mv = 0.f, kvv = 0.f;
#pragma unroll
    for (int c = 0; c < 32; ++c) {
        float4 w = w4[c], a = hv[c], k2 = kv[c];
        mv  += w.x * a.x  + w.y * a.y  + w.z * a.z  + w.w * a.w;
        kvv += w.x * k2.x + w.y * k2.y + w.z * k2.z + w.w * k2.w;
    }
#pragma unroll
    for (int off = 1; off < 8; off <<= 1) {
        mv  += __shfl_xor(mv, off);
        kvv += __shfl_xor(kvv, off);
    }
    if (sl == 0) {
        mvn[b * HIDD + j] = mv * invlen;
        kvn[b * HIDD + j] = kvv * invlen;
    }
}

// K5: out[b,s,j] = q_score[b,s,j/64]*mvn[b,j] + kvn[b,j], float4 stores.
// grid 16384, block 256, 8 elems/thread
__global__ __launch_bounds__(256) void k_out(const float* __restrict__ qsb,
                                             const float* __restrict__ mvn,
                                             const float* __restrict__ kvn,
                                             float* __restrict__ outp) {
    size_t e0 = ((size_t)blockIdx.x * 256 + threadIdx.x) * 8;
    int b   = (int)(e0 >> 22);                 // 4096*1024 = 2^22
    int rem = (int)(e0 & ((1u << 22) - 1));
    int s   = rem >> 10;
    int j   = rem & 1023;

    float q = qsb[(size_t)(b * SS + s) * 16 + (j >> 6)];
    const float4* mv4 = reinterpret_cast<const float4*>(mvn + b * HIDD + j);
    const float4* kv4 = reinterpret_cast<const float4*>(kvn + b * HIDD + j);
    float4 m0 = mv4[0], m1 = mv4[1];
    float4 k0 = kv4[0], k1 = kv4[1];

    float4 o0, o1;
    o0.x = q * m0.x + k0.x;  o0.y = q * m0.y + k0.y;
    o0.z = q * m0.z + k0.z;  o0.w = q * m0.w + k0.w;
    o1.x = q * m1.x + k1.x;  o1.y = q * m1.y + k1.y;
    o1.z = q * m1.z + k1.z;  o1.w = q * m1.w + k1.w;

    float4* op = reinterpret_cast<float4*>(outp + e0);
    op[0] = o0;
    op[1] = o1;
}

extern "C" void kernel_launch(void* const* d_in, const int* in_sizes, int n_in,
                              void* d_out, int out_size, void* d_ws, size_t ws_size,
                              hipStream_t stream) {
    const float* hid  = (const float*)d_in[0];   // (B,S,HID)
    const float* mask = (const float*)d_in[1];   // (B,1,1,S)
    const float* Wq   = (const float*)d_in[2];   // (HID,HID)
    const float* Wk   = (const float*)d_in[3];
    const float* Wv   = (const float*)d_in[4];
    const float* aw   = (const float*)d_in[5];   // (H,1,DH)
    float* outp = (float*)d_out;

    float* ws   = (float*)d_ws;
    unsigned short* bpack = (unsigned short*)ws; // 65536 ushort = 32768 floats
    float* qsb  = ws + 32768;               // 8*4096*16 = 524288
    float* ksb  = qsb + 524288;             // 8*4096*20 = 655360
    float* ksh  = ksb + 655360;             // 8*16*1024 = 131072
    float* hsum = ksh + 131072;             // 8*1024   = 8192
    float* mvn  = hsum + 8192;              // 8192
    float* kvn  = mvn + 8192;               // 8192
    float* part = kvn + 8192;               // 64*8*17*1024 = 8912896 (~35.7 MB)

    k_prep  <<<dim3(4, 16, 2), 256, 0, stream>>>(Wq, Wk, aw, bpack);
    k_scores<<<dim3(512),      256, 0, stream>>>(hid, mask, bpack, qsb, ksb);
    k_ksh   <<<dim3(64, 8),    256, 0, stream>>>(hid, ksb, part);
    k_red   <<<dim3(544),      256, 0, stream>>>(part, ksh, hsum);
    k_fin   <<<dim3(8, 32),    256, 0, stream>>>(Wv, mask, hsum, ksh, mvn, kvn);
    k_out   <<<dim3(16384),    256, 0, stream>>>(qsb, mvn, kvn, outp);
}